// Round 6
// baseline (534.869 us; speedup 1.0000x reference)
//
#include <hip/hip_runtime.h>
#include <math.h>

// GATv2 (in_ch=1, edge_dim=1, H=2, C=64) + fc, collapsed to rank-1/rank-2 algebra.
//
// Round 11: k_bin stall surgery. R9/R10 showed dur invariant to residency
// (occ 20->30%, dur ~49) => per-wave stalls, not starvation. Changes:
//  (1) FULL unroll of both 16-iter weight loops (compiler batches/hoists the
//      96 uniform s_loads instead of waitcnt every 4 channels); LDS slot-claim
//      atomics moved BEFORE the FMA loop (only need dst) to hide under compute.
//  (2) offsT transposed-scatter (4B every 6.2KB, 1.2M line-RMWs, WRITE_SIZE
//      64.5 vs 30.5 MB algorithmic) replaced by coalesced offs[s][b] write +
//      new k_xpose tiled transpose -> offsT[b][s] for k_reduce (unchanged).
//
// ws: rec[S_BLOCKS*1024] int4 | offs[S_BLOCKS*(NB+1)] int |
//     offsT[(NB+1)*S_BLOCKS] int | S[2N] f32 | C[1152] f32 |
//     Spart[NB*P*128*6] f32

#define LRELU_A1 0.6f   // leakyrelu(v) = 0.6 v + 0.4 |v|  (slope 0.2)
#define LRELU_A2 0.4f
#define TB       256
#define EPB      1024   // edges per bin block
#define NE       (EPB / TB)  // 4 edges per thread
#define NPB      128    // nodes per bucket (dst>>7)
#define NB_MAX   1024
#define SW       512    // sort window (records)
#define TSZ      32     // transpose tile

__global__ void k_prep(const unsigned int* __restrict__ ei,
                       const float* __restrict__ att,
                       const float* __restrict__ W_l,
                       const float* __restrict__ b_l, const float* __restrict__ b_r,
                       const float* __restrict__ bias_out,
                       const float* __restrict__ W_fc, const float* __restrict__ b_fc,
                       float* __restrict__ C) {
  int j = threadIdx.x;
  unsigned long long nz = __ballot(j < 32 && ei[2 * j + 1] != 0u);
  if (j == 0) ((int*)C)[1024] = (nz == 0ull) ? 1 : 0;   // 1 => int64 indices
  if (j >= 128) return;
  float a = att[j];
  C[j] = LRELU_A1 * a;          // A1
  C[128 + j] = LRELU_A2 * a;    // A2
  C[256 + j] = b_l[j] + b_r[j]; // BASE
  const float* wrow = W_fc + j * 256;
  float u0 = 0.f, u1 = 0.f, v0 = 0.f, v1 = 0.f, cb = b_fc[j];
  for (int c = 0; c < 64; c++) {
    u0 = fmaf(W_l[c],      wrow[c],       u0);
    u1 = fmaf(W_l[64 + c], wrow[64 + c],  u1);
    v0 = fmaf(W_l[c],      wrow[128 + c], v0);
    v1 = fmaf(W_l[64 + c], wrow[192 + c], v1);
  }
  for (int t = 0; t < 128; t++) {
    float gb = b_l[t] + bias_out[t];
    cb = fmaf(gb, wrow[t] + wrow[128 + t], cb);
  }
  C[384 + j] = u0;  // U0
  C[512 + j] = u1;  // U1
  C[640 + j] = v0;  // V0
  C[768 + j] = v1;  // V1
  C[896 + j] = cb;  // CB
}

#define CH_STEP(comp, ACC, i)                                                      \
  do {                                                                             \
    float v_ = fmaf(xs8[i], wl.comp, fmaf(xt8[i], wr.comp, fmaf(ae8[i], we.comp, bb.comp))); \
    ACC[i] = fmaf(a2.comp, fabsf(v_), fmaf(a1.comp, v_, ACC[i]));                  \
  } while (0)

__global__ __launch_bounds__(TB, 4) void k_bin(
    const float* __restrict__ x, const int* __restrict__ ei,
    const float* __restrict__ ea,
    const float* __restrict__ WL, const float* __restrict__ WR,
    const float* __restrict__ WE, const float* __restrict__ C,
    int4* __restrict__ rec, int* __restrict__ offs,
    int NB, int S_BLOCKS, int E) {
  __shared__ int cnt[NB_MAX];
  __shared__ int pfx[NB_MAX + 1];
  __shared__ int wsum[4];
  const int tid = threadIdx.x;
  for (int i = tid; i < NB_MAX; i += TB) cnt[i] = 0;
  __syncthreads();

  const int e0 = blockIdx.x * EPB;
  const bool w64 = ((const int*)C)[1024] != 0;
  const float* A1 = C;
  const float* A2 = C + 128;
  const float* BASE = C + 256;

  int de8[NE];
  float ae8[NE], xs8[NE], xt8[NE];
  bool ok[NE];
#pragma unroll
  for (int i = 0; i < NE; i++) {
    int e = e0 + i * TB + tid;   // coalesced per round
    ok[i] = (e < E);
    int ee = ok[i] ? e : 0;
    int s_ = w64 ? ei[2 * ee] : ei[ee];
    int d_ = w64 ? ei[2 * (E + ee)] : ei[E + ee];
    de8[i] = d_;
    ae8[i] = ea[ee];
    xs8[i] = x[s_];
    xt8[i] = x[d_];
  }
  // claim LDS slots EARLY (only needs dst) -> atomic latency hides under FMA
  int b8[NE], slot8[NE];
#pragma unroll
  for (int i = 0; i < NE; i++) {
    b8[i] = de8[i] >> 7;
    slot8[i] = ok[i] ? atomicAdd(&cnt[b8[i]], 1) : 0;
  }
  float acc0[NE], acc1[NE];
#pragma unroll
  for (int i = 0; i < NE; i++) { acc0[i] = 0.f; acc1[i] = 0.f; }
#pragma unroll
  for (int jb = 0; jb < 64; jb += 4) {
    float4 wl = *(const float4*)(WL + jb);
    float4 wr = *(const float4*)(WR + jb);
    float4 we = *(const float4*)(WE + jb);
    float4 bb = *(const float4*)(BASE + jb);
    float4 a1 = *(const float4*)(A1 + jb);
    float4 a2 = *(const float4*)(A2 + jb);
#pragma unroll
    for (int i = 0; i < NE; i++) {
      CH_STEP(x, acc0, i); CH_STEP(y, acc0, i); CH_STEP(z, acc0, i); CH_STEP(w, acc0, i);
    }
  }
#pragma unroll
  for (int jb = 64; jb < 128; jb += 4) {
    float4 wl = *(const float4*)(WL + jb);
    float4 wr = *(const float4*)(WR + jb);
    float4 we = *(const float4*)(WE + jb);
    float4 bb = *(const float4*)(BASE + jb);
    float4 a1 = *(const float4*)(A1 + jb);
    float4 a2 = *(const float4*)(A2 + jb);
#pragma unroll
    for (int i = 0; i < NE; i++) {
      CH_STEP(x, acc1, i); CH_STEP(y, acc1, i); CH_STEP(z, acc1, i); CH_STEP(w, acc1, i);
    }
  }
  // payload pack
  int p0[NE], p1[NE], p2[NE], p3[NE];
#pragma unroll
  for (int i = 0; i < NE; i++) {
    p0[i] = __float_as_int(__expf(acc0[i]));
    p1[i] = __float_as_int(__expf(acc1[i]));
    p2[i] = __float_as_int(xs8[i]);
    p3[i] = (int)((__float_as_uint(ae8[i]) & ~127u) | (unsigned)(de8[i] & 127));
  }
  __syncthreads();
  // exclusive scan of cnt[0..NB): per-thread 4 buckets, wave-shfl scan
  int l4[4], mysum = 0;
#pragma unroll
  for (int j = 0; j < 4; j++) {
    int idx = tid * 4 + j;
    l4[j] = (idx < NB) ? cnt[idx] : 0;
    mysum += l4[j];
  }
  const int lane = tid & 63, wv = tid >> 6;
  int inc = mysum;
#pragma unroll
  for (int d = 1; d < 64; d <<= 1) {
    int t = __shfl_up(inc, d);
    if (lane >= d) inc += t;
  }
  if (lane == 63) wsum[wv] = inc;
  __syncthreads();
  int wbase = 0;
#pragma unroll
  for (int w = 0; w < 4; w++) if (w < wv) wbase += wsum[w];
  int run = wbase + inc - mysum;
#pragma unroll
  for (int j = 0; j < 4; j++) {
    int idx = tid * 4 + j;
    if (idx < NB) { pfx[idx] = run; run += l4[j]; }
  }
  if (tid == 0) pfx[NB] = wsum[0] + wsum[1] + wsum[2] + wsum[3];
  __syncthreads();
  // coalesced offs[s][b] write (783 contiguous ints per block)
  int* myoffs = offs + (size_t)blockIdx.x * (NB + 1);
  for (int b = tid; b <= NB; b += TB) myoffs[b] = pfx[b];
  // direct-indexed drain from registers (random within 16KB block region; L2-local)
  int4* myrec = rec + (size_t)blockIdx.x * EPB;
#pragma unroll
  for (int i = 0; i < NE; i++) {
    if (ok[i]) myrec[pfx[b8[i]] + slot8[i]] = make_int4(p0[i], p1[i], p2[i], p3[i]);
  }
}

// Tiled transpose: offs[s][b] (s<S_BLOCKS rows, R=NB+1 cols) -> offsT[b][s].
// Both sides coalesced; kills the 4B-every-6.2KB line-RMW scatter k_bin had.
__global__ __launch_bounds__(256) void k_xpose(const int* __restrict__ offs,
                                               int* __restrict__ offsT,
                                               int R, int SB) {
  __shared__ int tile[TSZ][TSZ + 1];
  const int b0 = blockIdx.x * TSZ;   // col tile in offs (b axis)
  const int s0 = blockIdx.y * TSZ;   // row tile in offs (s axis)
  const int tx = threadIdx.x & 31, ty = threadIdx.x >> 5;  // 32x8
  for (int i = ty; i < TSZ; i += 8) {
    int s = s0 + i, b = b0 + tx;
    tile[i][tx] = (s < SB && b < R) ? offs[(size_t)s * R + b] : 0;
  }
  __syncthreads();
  for (int i = ty; i < TSZ; i += 8) {
    int b = b0 + i, s = s0 + tx;
    if (b < R && s < SB) offsT[(size_t)b * SB + s] = tile[tx][i];
  }
}

// One block per (bucket, part). part covers segments s in
// [part*SPP, min((part+1)*SPP, S_BLOCKS)), SPP <= 2*TB (host invariant).
// Thread tid owns segment tid (A) and tid+TB (B) as named scalars (no spill).
// Windowed counting sort by 7-bit node key, then per-node register reduction.
__global__ __launch_bounds__(TB, 4) void k_reduce(
    const int4* __restrict__ rec, const int* __restrict__ offsT,
    float* __restrict__ Spart, int S_BLOCKS, int SPP) {
  __shared__ int4 sorted[SW];          // 8 KB
  __shared__ int lut[SW];              // 2 KB
  __shared__ int cnt[NPB];             // histogram
  __shared__ int pos0[NPB];            // exclusive scan of cnt
  __shared__ int claim[NPB];           // scatter cursor
  __shared__ int wsum[4];
  const int tid = threadIdx.x;
  const int b = blockIdx.x;            // bucket
  const int part = blockIdx.y;

  // segment A = part*SPP + tid, segment B = part*SPP + tid + TB
  const int sA = part * SPP + tid;
  const int sB = sA + TB;
  int stA = 0, lenA = 0, stB = 0, lenB = 0;
  if (tid < SPP && sA < S_BLOCKS) {
    stA  = offsT[(size_t)b * S_BLOCKS + sA];
    lenA = offsT[(size_t)(b + 1) * S_BLOCKS + sA] - stA;
  }
  if (TB + tid < SPP && sB < S_BLOCKS) {
    stB  = offsT[(size_t)b * S_BLOCKS + sB];
    lenB = offsT[(size_t)(b + 1) * S_BLOCKS + sB] - stB;
  }
  const int rbA = sA * EPB + stA;      // global rec index of segment A start
  const int rbB = sB * EPB + stB;
  const int mysum = lenA + lenB;
  if (tid < NPB) cnt[tid] = 0;
  // wave-shfl exclusive scan of per-thread record counts
  const int lane = tid & 63, wv = tid >> 6;
  int inc = mysum;
#pragma unroll
  for (int d = 1; d < 64; d <<= 1) {
    int t = __shfl_up(inc, d);
    if (lane >= d) inc += t;
  }
  if (lane == 63) wsum[wv] = inc;
  __syncthreads();
  int wbase = 0;
#pragma unroll
  for (int w = 0; w < 4; w++) if (w < wv) wbase += wsum[w];
  const int T = wsum[0] + wsum[1] + wsum[2] + wsum[3];
  const int bsA = wbase + inc - mysum; // this thread's strip: [bsA, bsA+lenA+lenB)
  const int bsB = bsA + lenA;

  // per-node register accumulators (threads < NPB)
  float r0 = 0.f, r1 = 0.f, r2 = 0.f, r3 = 0.f, r4 = 0.f;
  int rc = 0;

  for (int w0 = 0; w0 < T; w0 += SW) {
    const int w1 = min(w0 + SW, T);
    // fill lut[w0..w1): each segment-owner scatters its records' rec indices
    {
      int lo = max(bsA, w0), hi = min(bsA + lenA, w1);
      for (int k = lo; k < hi; k++) lut[k - w0] = rbA + (k - bsA);
      lo = max(bsB, w0); hi = min(bsB + lenB, w1);
      for (int k = lo; k < hi; k++) lut[k - w0] = rbB + (k - bsB);
    }
    __syncthreads();
    // pass A: histogram node keys (no-return u32 atomic)
    for (int i = w0 + tid; i < w1; i += TB) {
      int4 r = rec[(size_t)(unsigned)lut[i - w0]];
      atomicAdd(&cnt[(int)((unsigned)r.w & 127u)], 1);
    }
    __syncthreads();
    // wave 0: exclusive scan of cnt[0..128) via shfl, init claim cursors
    if (tid < 64) {
      int c0 = cnt[2 * tid], c1 = cnt[2 * tid + 1];
      int s = c0 + c1;
      for (int d = 1; d < 64; d <<= 1) {
        int t = __shfl_up(s, d);
        if (tid >= d) s += t;
      }
      int excl = s - (c0 + c1);
      pos0[2 * tid] = excl;
      pos0[2 * tid + 1] = excl + c0;
      claim[2 * tid] = excl;
      claim[2 * tid + 1] = excl + c0;
    }
    __syncthreads();
    // pass B: re-read (cache-hot), claim sorted slot, scatter into LDS
    for (int i = w0 + tid; i < w1; i += TB) {
      int4 r = rec[(size_t)(unsigned)lut[i - w0]];
      int node = (int)((unsigned)r.w & 127u);
      int slot = atomicAdd(&claim[node], 1);
      sorted[slot] = r;
    }
    __syncthreads();
    // pass C: thread n walks node n's contiguous run, accumulates in regs
    if (tid < NPB) {
      int p = pos0[tid], c = cnt[tid];
      for (int k = 0; k < c; k++) {
        int4 r = sorted[p + k];
        float e0v = __int_as_float(r.x);
        float e1v = __int_as_float(r.y);
        float xsv = __int_as_float(r.z);
        float aev = __uint_as_float((unsigned)r.w & ~127u);
        r0 += e0v;
        r1 += e0v * xsv;
        r2 += e1v;
        r3 += e1v * xsv;
        r4 += aev;
      }
      rc += c;
      cnt[tid] = 0;   // reset for next window (after use)
    }
    __syncthreads();
  }
  // drain: 6 floats per node, contiguous 24 B per thread
  if (tid < NPB) {
    float* out = Spart + ((size_t)b * gridDim.y + part) * (NPB * 6) + tid * 6;
    out[0] = r0; out[1] = r1; out[2] = r2;
    out[3] = r3; out[4] = r4; out[5] = (float)rc;
  }
}

// Sum the P partials per node, then fused self-loop + S finalize.
__global__ __launch_bounds__(256) void k_fin(
    const float* __restrict__ x,
    const float* __restrict__ WL, const float* __restrict__ WR,
    const float* __restrict__ WE, const float* __restrict__ C,
    const float* __restrict__ Spart, float* __restrict__ S,
    int N, int P) {
  int n = blockIdx.x * blockDim.x + threadIdx.x;
  if (n >= N) return;
  int b = n >> 7, t = n & 127;
  const float* q0 = Spart + ((size_t)b * P) * (NPB * 6) + t * 6;
  float den0 = 0.f, num0 = 0.f, den1 = 0.f, num1 = 0.f, asum = 0.f, cntv = 0.f;
  for (int p = 0; p < P; p++) {
    const float* q = q0 + (size_t)p * (NPB * 6);
    float2 v0 = *(const float2*)(q);
    float2 v1 = *(const float2*)(q + 2);
    float2 v2 = *(const float2*)(q + 4);
    den0 += v0.x; num0 += v0.y;
    den1 += v1.x; num1 += v1.y;
    asum += v2.x; cntv += v2.y;
  }
  const float* A1 = C;
  const float* A2 = C + 128;
  const float* BASE = C + 256;
  float xn = x[n];
  float am = asum / fmaxf(cntv, 1.0f);
  float acc0 = 0.f, acc1 = 0.f;
#pragma unroll 4
  for (int jb = 0; jb < 64; jb += 4) {
    float4 wl = *(const float4*)(WL + jb);
    float4 wr = *(const float4*)(WR + jb);
    float4 we = *(const float4*)(WE + jb);
    float4 bb = *(const float4*)(BASE + jb);
    float4 a1 = *(const float4*)(A1 + jb);
    float4 a2 = *(const float4*)(A2 + jb);
    float v;
    v = fmaf(xn, wl.x + wr.x, fmaf(am, we.x, bb.x)); acc0 = fmaf(a2.x, fabsf(v), fmaf(a1.x, v, acc0));
    v = fmaf(xn, wl.y + wr.y, fmaf(am, we.y, bb.y)); acc0 = fmaf(a2.y, fabsf(v), fmaf(a1.y, v, acc0));
    v = fmaf(xn, wl.z + wr.z, fmaf(am, we.z, bb.z)); acc0 = fmaf(a2.z, fabsf(v), fmaf(a1.z, v, acc0));
    v = fmaf(xn, wl.w + wr.w, fmaf(am, we.w, bb.w)); acc0 = fmaf(a2.w, fabsf(v), fmaf(a1.w, v, acc0));
  }
#pragma unroll 4
  for (int jb = 64; jb < 128; jb += 4) {
    float4 wl = *(const float4*)(WL + jb);
    float4 wr = *(const float4*)(WR + jb);
    float4 we = *(const float4*)(WE + jb);
    float4 bb = *(const float4*)(BASE + jb);
    float4 a1 = *(const float4*)(A1 + jb);
    float4 a2 = *(const float4*)(A2 + jb);
    float v;
    v = fmaf(xn, wl.x + wr.x, fmaf(am, we.x, bb.x)); acc1 = fmaf(a2.x, fabsf(v), fmaf(a1.x, v, acc1));
    v = fmaf(xn, wl.y + wr.y, fmaf(am, we.y, bb.y)); acc1 = fmaf(a2.y, fabsf(v), fmaf(a1.y, v, acc1));
    v = fmaf(xn, wl.z + wr.z, fmaf(am, we.z, bb.z)); acc1 = fmaf(a2.z, fabsf(v), fmaf(a1.z, v, acc1));
    v = fmaf(xn, wl.w + wr.w, fmaf(am, we.w, bb.w)); acc1 = fmaf(a2.w, fabsf(v), fmaf(a1.w, v, acc1));
  }
  float s0 = __expf(acc0), s1 = __expf(acc1);
  float2 sv;
  sv.x = (num0 + s0 * xn) / (den0 + s0);
  sv.y = (num1 + s1 * xn) / (den1 + s1);
  *(float2*)(S + 2 * n) = sv;
}

__global__ __launch_bounds__(256) void k_out(
    const float* __restrict__ S, const float* __restrict__ C,
    const int* __restrict__ tgtp, float* __restrict__ out, int N) {
  int g = blockIdx.x * blockDim.x + threadIdx.x;
  if (g >= N * 32) return;
  int n = g >> 5;
  int kq = (g & 31) * 4;
  int T = tgtp[0];  // low word valid for int32 and little-endian int64
  float s0t = S[2 * T], s1t = S[2 * T + 1];
  float2 s = *(const float2*)(S + 2 * n);
  float4 u0 = *(const float4*)(C + 384 + kq);
  float4 u1 = *(const float4*)(C + 512 + kq);
  float4 v0 = *(const float4*)(C + 640 + kq);
  float4 v1 = *(const float4*)(C + 768 + kq);
  float4 cb = *(const float4*)(C + 896 + kq);
  float4 o;
  o.x = fmaf(s.x, u0.x, fmaf(s.y, u1.x, fmaf(s0t, v0.x, fmaf(s1t, v1.x, cb.x))));
  o.y = fmaf(s.x, u0.y, fmaf(s.y, u1.y, fmaf(s0t, v0.y, fmaf(s1t, v1.y, cb.y))));
  o.z = fmaf(s.x, u0.z, fmaf(s.y, u1.z, fmaf(s0t, v0.z, fmaf(s1t, v1.z, cb.z))));
  o.w = fmaf(s.x, u0.w, fmaf(s.y, u1.w, fmaf(s0t, v0.w, fmaf(s1t, v1.w, cb.w))));
  *(float4*)(out + n * 128 + kq) = o;
}

extern "C" void kernel_launch(void* const* d_in, const int* in_sizes, int n_in,
                              void* d_out, int out_size, void* d_ws, size_t ws_size,
                              hipStream_t stream) {
  const float* x        = (const float*)d_in[0];
  const int*   ei       = (const int*)d_in[1];
  const float* ea       = (const float*)d_in[2];
  const int*   tgt      = (const int*)d_in[3];
  const float* W_l      = (const float*)d_in[4];
  const float* b_l      = (const float*)d_in[5];
  const float* W_r      = (const float*)d_in[6];
  const float* b_r      = (const float*)d_in[7];
  const float* W_e      = (const float*)d_in[8];
  const float* att      = (const float*)d_in[9];
  const float* bias_out = (const float*)d_in[10];
  const float* W_fc     = (const float*)d_in[11];
  const float* b_fc     = (const float*)d_in[12];

  const int N = in_sizes[0];
  const int E = in_sizes[2];
  const int NB = (N + NPB - 1) / NPB;          // 782 buckets
  const int S_BLOCKS = (E + EPB - 1) / EPB;    // 1563 bin blocks

  const size_t sz_rec   = (size_t)S_BLOCKS * EPB * 16;
  const size_t sz_offs  = (size_t)S_BLOCKS * (NB + 1) * 4;  // row-major
  const size_t sz_offsT = (size_t)(NB + 1) * S_BLOCKS * 4;  // transposed
  const size_t sz_S     = (size_t)2 * N * 4;
  const size_t sz_C     = 4608;
  // largest P in {8,4,2} whose partial slab fits; SPP must stay <= 2*TB (=512)
  int P = 8;
  while (P > 2 &&
         sz_rec + sz_offs + sz_offsT + sz_S + sz_C +
             (size_t)NB * P * NPB * 6 * 4 > ws_size)
    P >>= 1;
  const int SPP = (S_BLOCKS + P - 1) / P;      // 196 @ P=8, 391 @ P=4

  char* p = (char*)d_ws;
  int4*  rec   = (int4*)p;                      p += sz_rec;
  int*   offs  = (int*)p;                       p += sz_offs;
  int*   offsT = (int*)p;                       p += sz_offsT;
  float* S     = (float*)p;                     p += sz_S;
  float* C     = (float*)p;                     p += sz_C;
  float* Spart = (float*)p;

  k_prep<<<1, 128, 0, stream>>>((const unsigned int*)ei, att, W_l, b_l, b_r,
                                bias_out, W_fc, b_fc, C);
  k_bin<<<S_BLOCKS, TB, 0, stream>>>(x, ei, ea, W_l, W_r, W_e, C,
                                     rec, offs, NB, S_BLOCKS, E);
  k_xpose<<<dim3((NB + 1 + TSZ - 1) / TSZ, (S_BLOCKS + TSZ - 1) / TSZ),
            256, 0, stream>>>(offs, offsT, NB + 1, S_BLOCKS);
  k_reduce<<<dim3(NB, P), TB, 0, stream>>>(rec, offsT, Spart, S_BLOCKS, SPP);
  k_fin<<<(N + 255) / 256, 256, 0, stream>>>(x, W_l, W_r, W_e, C, Spart, S, N, P);
  k_out<<<(N * 32 + 255) / 256, 256, 0, stream>>>(S, C, tgt, (float*)d_out, N);
}

// Round 8
// 208.581 us; speedup vs baseline: 2.5643x; 2.5643x over previous
//
#include <hip/hip_runtime.h>
#include <math.h>

// GATv2 (in_ch=1, edge_dim=1, H=2, C=64) + fc, collapsed to rank-1/rank-2 algebra.
//
// Round 13 (= round 12 resubmit after infra failure): revert R11's
// full-unroll (AGPR-spill VALU storm: VALUBusy 76%, 373us) back to the proven
// R10 k_bin body (unroll 2, claim in payload phase, 48.7us measured). KEEP
// R11's one confirmed win: coalesced offs[s][b] write + k_xpose tiled
// transpose (WRITE_SIZE 64.5->48.5 MB, kills the 4B-every-6.2KB offsT
// line-RMW scatter).
//
// ws: rec[S_BLOCKS*1024] int4 | offs[S_BLOCKS*(NB+1)] int |
//     offsT[(NB+1)*S_BLOCKS] int | S[2N] f32 | C[1152] f32 |
//     Spart[NB*P*128*6] f32

#define LRELU_A1 0.6f   // leakyrelu(v) = 0.6 v + 0.4 |v|  (slope 0.2)
#define LRELU_A2 0.4f
#define TB       256
#define EPB      1024   // edges per bin block
#define NE       (EPB / TB)  // 4 edges per thread
#define NPB      128    // nodes per bucket (dst>>7)
#define NB_MAX   1024
#define SW       512    // sort window (records)
#define TSZ      32     // transpose tile

__global__ void k_prep(const unsigned int* __restrict__ ei,
                       const float* __restrict__ att,
                       const float* __restrict__ W_l,
                       const float* __restrict__ b_l, const float* __restrict__ b_r,
                       const float* __restrict__ bias_out,
                       const float* __restrict__ W_fc, const float* __restrict__ b_fc,
                       float* __restrict__ C) {
  int j = threadIdx.x;
  unsigned long long nz = __ballot(j < 32 && ei[2 * j + 1] != 0u);
  if (j == 0) ((int*)C)[1024] = (nz == 0ull) ? 1 : 0;   // 1 => int64 indices
  if (j >= 128) return;
  float a = att[j];
  C[j] = LRELU_A1 * a;          // A1
  C[128 + j] = LRELU_A2 * a;    // A2
  C[256 + j] = b_l[j] + b_r[j]; // BASE
  const float* wrow = W_fc + j * 256;
  float u0 = 0.f, u1 = 0.f, v0 = 0.f, v1 = 0.f, cb = b_fc[j];
  for (int c = 0; c < 64; c++) {
    u0 = fmaf(W_l[c],      wrow[c],       u0);
    u1 = fmaf(W_l[64 + c], wrow[64 + c],  u1);
    v0 = fmaf(W_l[c],      wrow[128 + c], v0);
    v1 = fmaf(W_l[64 + c], wrow[192 + c], v1);
  }
  for (int t = 0; t < 128; t++) {
    float gb = b_l[t] + bias_out[t];
    cb = fmaf(gb, wrow[t] + wrow[128 + t], cb);
  }
  C[384 + j] = u0;  // U0
  C[512 + j] = u1;  // U1
  C[640 + j] = v0;  // V0
  C[768 + j] = v1;  // V1
  C[896 + j] = cb;  // CB
}

#define CH_STEP(comp, ACC, i)                                                      \
  do {                                                                             \
    float v_ = fmaf(xs8[i], wl.comp, fmaf(xt8[i], wr.comp, fmaf(ae8[i], we.comp, bb.comp))); \
    ACC[i] = fmaf(a2.comp, fabsf(v_), fmaf(a1.comp, v_, ACC[i]));                  \
  } while (0)

__global__ __launch_bounds__(TB, 4) void k_bin(
    const float* __restrict__ x, const int* __restrict__ ei,
    const float* __restrict__ ea,
    const float* __restrict__ WL, const float* __restrict__ WR,
    const float* __restrict__ WE, const float* __restrict__ C,
    int4* __restrict__ rec, int* __restrict__ offs,
    int NB, int S_BLOCKS, int E) {
  __shared__ int cnt[NB_MAX];
  __shared__ int pfx[NB_MAX + 1];
  __shared__ int wsum[4];
  const int tid = threadIdx.x;
  for (int i = tid; i < NB_MAX; i += TB) cnt[i] = 0;
  __syncthreads();

  const int e0 = blockIdx.x * EPB;
  const bool w64 = ((const int*)C)[1024] != 0;
  const float* A1 = C;
  const float* A2 = C + 128;
  const float* BASE = C + 256;

  int de8[NE];
  float ae8[NE], xs8[NE], xt8[NE];
  bool ok[NE];
#pragma unroll
  for (int i = 0; i < NE; i++) {
    int e = e0 + i * TB + tid;   // coalesced per round
    ok[i] = (e < E);
    int ee = ok[i] ? e : 0;
    int s_ = w64 ? ei[2 * ee] : ei[ee];
    int d_ = w64 ? ei[2 * (E + ee)] : ei[E + ee];
    de8[i] = d_;
    ae8[i] = ea[ee];
    xs8[i] = x[s_];
    xt8[i] = x[d_];
  }
  float acc0[NE], acc1[NE];
#pragma unroll
  for (int i = 0; i < NE; i++) { acc0[i] = 0.f; acc1[i] = 0.f; }
#pragma unroll 2
  for (int jb = 0; jb < 64; jb += 4) {
    float4 wl = *(const float4*)(WL + jb);
    float4 wr = *(const float4*)(WR + jb);
    float4 we = *(const float4*)(WE + jb);
    float4 bb = *(const float4*)(BASE + jb);
    float4 a1 = *(const float4*)(A1 + jb);
    float4 a2 = *(const float4*)(A2 + jb);
#pragma unroll
    for (int i = 0; i < NE; i++) {
      CH_STEP(x, acc0, i); CH_STEP(y, acc0, i); CH_STEP(z, acc0, i); CH_STEP(w, acc0, i);
    }
  }
#pragma unroll 2
  for (int jb = 64; jb < 128; jb += 4) {
    float4 wl = *(const float4*)(WL + jb);
    float4 wr = *(const float4*)(WR + jb);
    float4 we = *(const float4*)(WE + jb);
    float4 bb = *(const float4*)(BASE + jb);
    float4 a1 = *(const float4*)(A1 + jb);
    float4 a2 = *(const float4*)(A2 + jb);
#pragma unroll
    for (int i = 0; i < NE; i++) {
      CH_STEP(x, acc1, i); CH_STEP(y, acc1, i); CH_STEP(z, acc1, i); CH_STEP(w, acc1, i);
    }
  }
  // payload -> registers; claim slots in LDS
  int b8[NE], slot8[NE], p0[NE], p1[NE], p2[NE], p3[NE];
#pragma unroll
  for (int i = 0; i < NE; i++) {
    int d_ = de8[i];
    b8[i] = d_ >> 7;
    p0[i] = __float_as_int(__expf(acc0[i]));
    p1[i] = __float_as_int(__expf(acc1[i]));
    p2[i] = __float_as_int(xs8[i]);
    p3[i] = (int)((__float_as_uint(ae8[i]) & ~127u) | (unsigned)(d_ & 127));
    slot8[i] = ok[i] ? atomicAdd(&cnt[b8[i]], 1) : 0;
  }
  __syncthreads();
  // exclusive scan of cnt[0..NB): per-thread 4 buckets, wave-shfl scan
  int l4[4], mysum = 0;
#pragma unroll
  for (int j = 0; j < 4; j++) {
    int idx = tid * 4 + j;
    l4[j] = (idx < NB) ? cnt[idx] : 0;
    mysum += l4[j];
  }
  const int lane = tid & 63, wv = tid >> 6;
  int inc = mysum;
#pragma unroll
  for (int d = 1; d < 64; d <<= 1) {
    int t = __shfl_up(inc, d);
    if (lane >= d) inc += t;
  }
  if (lane == 63) wsum[wv] = inc;
  __syncthreads();
  int wbase = 0;
#pragma unroll
  for (int w = 0; w < 4; w++) if (w < wv) wbase += wsum[w];
  int run = wbase + inc - mysum;
#pragma unroll
  for (int j = 0; j < 4; j++) {
    int idx = tid * 4 + j;
    if (idx < NB) { pfx[idx] = run; run += l4[j]; }
  }
  if (tid == 0) pfx[NB] = wsum[0] + wsum[1] + wsum[2] + wsum[3];
  __syncthreads();
  // coalesced offs[s][b] write (783 contiguous ints per block)
  int* myoffs = offs + (size_t)blockIdx.x * (NB + 1);
  for (int b = tid; b <= NB; b += TB) myoffs[b] = pfx[b];
  // direct-indexed drain from registers (random within 16KB block region; L2-local)
  int4* myrec = rec + (size_t)blockIdx.x * EPB;
#pragma unroll
  for (int i = 0; i < NE; i++) {
    if (ok[i]) myrec[pfx[b8[i]] + slot8[i]] = make_int4(p0[i], p1[i], p2[i], p3[i]);
  }
}

// Tiled transpose: offs[s][b] (s<S_BLOCKS rows, R=NB+1 cols) -> offsT[b][s].
// Both sides coalesced; kills the 4B-every-6.2KB line-RMW scatter k_bin had.
__global__ __launch_bounds__(256) void k_xpose(const int* __restrict__ offs,
                                               int* __restrict__ offsT,
                                               int R, int SB) {
  __shared__ int tile[TSZ][TSZ + 1];
  const int b0 = blockIdx.x * TSZ;   // col tile in offs (b axis)
  const int s0 = blockIdx.y * TSZ;   // row tile in offs (s axis)
  const int tx = threadIdx.x & 31, ty = threadIdx.x >> 5;  // 32x8
  for (int i = ty; i < TSZ; i += 8) {
    int s = s0 + i, b = b0 + tx;
    tile[i][tx] = (s < SB && b < R) ? offs[(size_t)s * R + b] : 0;
  }
  __syncthreads();
  for (int i = ty; i < TSZ; i += 8) {
    int b = b0 + i, s = s0 + tx;
    if (b < R && s < SB) offsT[(size_t)b * SB + s] = tile[tx][i];
  }
}

// One block per (bucket, part). part covers segments s in
// [part*SPP, min((part+1)*SPP, S_BLOCKS)), SPP <= 2*TB (host invariant).
// Thread tid owns segment tid (A) and tid+TB (B) as named scalars (no spill).
// Windowed counting sort by 7-bit node key, then per-node register reduction.
__global__ __launch_bounds__(TB, 4) void k_reduce(
    const int4* __restrict__ rec, const int* __restrict__ offsT,
    float* __restrict__ Spart, int S_BLOCKS, int SPP) {
  __shared__ int4 sorted[SW];          // 8 KB
  __shared__ int lut[SW];              // 2 KB
  __shared__ int cnt[NPB];             // histogram
  __shared__ int pos0[NPB];            // exclusive scan of cnt
  __shared__ int claim[NPB];           // scatter cursor
  __shared__ int wsum[4];
  const int tid = threadIdx.x;
  const int b = blockIdx.x;            // bucket
  const int part = blockIdx.y;

  // segment A = part*SPP + tid, segment B = part*SPP + tid + TB
  const int sA = part * SPP + tid;
  const int sB = sA + TB;
  int stA = 0, lenA = 0, stB = 0, lenB = 0;
  if (tid < SPP && sA < S_BLOCKS) {
    stA  = offsT[(size_t)b * S_BLOCKS + sA];
    lenA = offsT[(size_t)(b + 1) * S_BLOCKS + sA] - stA;
  }
  if (TB + tid < SPP && sB < S_BLOCKS) {
    stB  = offsT[(size_t)b * S_BLOCKS + sB];
    lenB = offsT[(size_t)(b + 1) * S_BLOCKS + sB] - stB;
  }
  const int rbA = sA * EPB + stA;      // global rec index of segment A start
  const int rbB = sB * EPB + stB;
  const int mysum = lenA + lenB;
  if (tid < NPB) cnt[tid] = 0;
  // wave-shfl exclusive scan of per-thread record counts
  const int lane = tid & 63, wv = tid >> 6;
  int inc = mysum;
#pragma unroll
  for (int d = 1; d < 64; d <<= 1) {
    int t = __shfl_up(inc, d);
    if (lane >= d) inc += t;
  }
  if (lane == 63) wsum[wv] = inc;
  __syncthreads();
  int wbase = 0;
#pragma unroll
  for (int w = 0; w < 4; w++) if (w < wv) wbase += wsum[w];
  const int T = wsum[0] + wsum[1] + wsum[2] + wsum[3];
  const int bsA = wbase + inc - mysum; // this thread's strip: [bsA, bsA+lenA+lenB)
  const int bsB = bsA + lenA;

  // per-node register accumulators (threads < NPB)
  float r0 = 0.f, r1 = 0.f, r2 = 0.f, r3 = 0.f, r4 = 0.f;
  int rc = 0;

  for (int w0 = 0; w0 < T; w0 += SW) {
    const int w1 = min(w0 + SW, T);
    // fill lut[w0..w1): each segment-owner scatters its records' rec indices
    {
      int lo = max(bsA, w0), hi = min(bsA + lenA, w1);
      for (int k = lo; k < hi; k++) lut[k - w0] = rbA + (k - bsA);
      lo = max(bsB, w0); hi = min(bsB + lenB, w1);
      for (int k = lo; k < hi; k++) lut[k - w0] = rbB + (k - bsB);
    }
    __syncthreads();
    // pass A: histogram node keys (no-return u32 atomic)
    for (int i = w0 + tid; i < w1; i += TB) {
      int4 r = rec[(size_t)(unsigned)lut[i - w0]];
      atomicAdd(&cnt[(int)((unsigned)r.w & 127u)], 1);
    }
    __syncthreads();
    // wave 0: exclusive scan of cnt[0..128) via shfl, init claim cursors
    if (tid < 64) {
      int c0 = cnt[2 * tid], c1 = cnt[2 * tid + 1];
      int s = c0 + c1;
      for (int d = 1; d < 64; d <<= 1) {
        int t = __shfl_up(s, d);
        if (tid >= d) s += t;
      }
      int excl = s - (c0 + c1);
      pos0[2 * tid] = excl;
      pos0[2 * tid + 1] = excl + c0;
      claim[2 * tid] = excl;
      claim[2 * tid + 1] = excl + c0;
    }
    __syncthreads();
    // pass B: re-read (cache-hot), claim sorted slot, scatter into LDS
    for (int i = w0 + tid; i < w1; i += TB) {
      int4 r = rec[(size_t)(unsigned)lut[i - w0]];
      int node = (int)((unsigned)r.w & 127u);
      int slot = atomicAdd(&claim[node], 1);
      sorted[slot] = r;
    }
    __syncthreads();
    // pass C: thread n walks node n's contiguous run, accumulates in regs
    if (tid < NPB) {
      int p = pos0[tid], c = cnt[tid];
      for (int k = 0; k < c; k++) {
        int4 r = sorted[p + k];
        float e0v = __int_as_float(r.x);
        float e1v = __int_as_float(r.y);
        float xsv = __int_as_float(r.z);
        float aev = __uint_as_float((unsigned)r.w & ~127u);
        r0 += e0v;
        r1 += e0v * xsv;
        r2 += e1v;
        r3 += e1v * xsv;
        r4 += aev;
      }
      rc += c;
      cnt[tid] = 0;   // reset for next window (after use)
    }
    __syncthreads();
  }
  // drain: 6 floats per node, contiguous 24 B per thread
  if (tid < NPB) {
    float* out = Spart + ((size_t)b * gridDim.y + part) * (NPB * 6) + tid * 6;
    out[0] = r0; out[1] = r1; out[2] = r2;
    out[3] = r3; out[4] = r4; out[5] = (float)rc;
  }
}

// Sum the P partials per node, then fused self-loop + S finalize.
__global__ __launch_bounds__(256) void k_fin(
    const float* __restrict__ x,
    const float* __restrict__ WL, const float* __restrict__ WR,
    const float* __restrict__ WE, const float* __restrict__ C,
    const float* __restrict__ Spart, float* __restrict__ S,
    int N, int P) {
  int n = blockIdx.x * blockDim.x + threadIdx.x;
  if (n >= N) return;
  int b = n >> 7, t = n & 127;
  const float* q0 = Spart + ((size_t)b * P) * (NPB * 6) + t * 6;
  float den0 = 0.f, num0 = 0.f, den1 = 0.f, num1 = 0.f, asum = 0.f, cntv = 0.f;
  for (int p = 0; p < P; p++) {
    const float* q = q0 + (size_t)p * (NPB * 6);
    float2 v0 = *(const float2*)(q);
    float2 v1 = *(const float2*)(q + 2);
    float2 v2 = *(const float2*)(q + 4);
    den0 += v0.x; num0 += v0.y;
    den1 += v1.x; num1 += v1.y;
    asum += v2.x; cntv += v2.y;
  }
  const float* A1 = C;
  const float* A2 = C + 128;
  const float* BASE = C + 256;
  float xn = x[n];
  float am = asum / fmaxf(cntv, 1.0f);
  float acc0 = 0.f, acc1 = 0.f;
#pragma unroll 4
  for (int jb = 0; jb < 64; jb += 4) {
    float4 wl = *(const float4*)(WL + jb);
    float4 wr = *(const float4*)(WR + jb);
    float4 we = *(const float4*)(WE + jb);
    float4 bb = *(const float4*)(BASE + jb);
    float4 a1 = *(const float4*)(A1 + jb);
    float4 a2 = *(const float4*)(A2 + jb);
    float v;
    v = fmaf(xn, wl.x + wr.x, fmaf(am, we.x, bb.x)); acc0 = fmaf(a2.x, fabsf(v), fmaf(a1.x, v, acc0));
    v = fmaf(xn, wl.y + wr.y, fmaf(am, we.y, bb.y)); acc0 = fmaf(a2.y, fabsf(v), fmaf(a1.y, v, acc0));
    v = fmaf(xn, wl.z + wr.z, fmaf(am, we.z, bb.z)); acc0 = fmaf(a2.z, fabsf(v), fmaf(a1.z, v, acc0));
    v = fmaf(xn, wl.w + wr.w, fmaf(am, we.w, bb.w)); acc0 = fmaf(a2.w, fabsf(v), fmaf(a1.w, v, acc0));
  }
#pragma unroll 4
  for (int jb = 64; jb < 128; jb += 4) {
    float4 wl = *(const float4*)(WL + jb);
    float4 wr = *(const float4*)(WR + jb);
    float4 we = *(const float4*)(WE + jb);
    float4 bb = *(const float4*)(BASE + jb);
    float4 a1 = *(const float4*)(A1 + jb);
    float4 a2 = *(const float4*)(A2 + jb);
    float v;
    v = fmaf(xn, wl.x + wr.x, fmaf(am, we.x, bb.x)); acc1 = fmaf(a2.x, fabsf(v), fmaf(a1.x, v, acc1));
    v = fmaf(xn, wl.y + wr.y, fmaf(am, we.y, bb.y)); acc1 = fmaf(a2.y, fabsf(v), fmaf(a1.y, v, acc1));
    v = fmaf(xn, wl.z + wr.z, fmaf(am, we.z, bb.z)); acc1 = fmaf(a2.z, fabsf(v), fmaf(a1.z, v, acc1));
    v = fmaf(xn, wl.w + wr.w, fmaf(am, we.w, bb.w)); acc1 = fmaf(a2.w, fabsf(v), fmaf(a1.w, v, acc1));
  }
  float s0 = __expf(acc0), s1 = __expf(acc1);
  float2 sv;
  sv.x = (num0 + s0 * xn) / (den0 + s0);
  sv.y = (num1 + s1 * xn) / (den1 + s1);
  *(float2*)(S + 2 * n) = sv;
}

__global__ __launch_bounds__(256) void k_out(
    const float* __restrict__ S, const float* __restrict__ C,
    const int* __restrict__ tgtp, float* __restrict__ out, int N) {
  int g = blockIdx.x * blockDim.x + threadIdx.x;
  if (g >= N * 32) return;
  int n = g >> 5;
  int kq = (g & 31) * 4;
  int T = tgtp[0];  // low word valid for int32 and little-endian int64
  float s0t = S[2 * T], s1t = S[2 * T + 1];
  float2 s = *(const float2*)(S + 2 * n);
  float4 u0 = *(const float4*)(C + 384 + kq);
  float4 u1 = *(const float4*)(C + 512 + kq);
  float4 v0 = *(const float4*)(C + 640 + kq);
  float4 v1 = *(const float4*)(C + 768 + kq);
  float4 cb = *(const float4*)(C + 896 + kq);
  float4 o;
  o.x = fmaf(s.x, u0.x, fmaf(s.y, u1.x, fmaf(s0t, v0.x, fmaf(s1t, v1.x, cb.x))));
  o.y = fmaf(s.x, u0.y, fmaf(s.y, u1.y, fmaf(s0t, v0.y, fmaf(s1t, v1.y, cb.y))));
  o.z = fmaf(s.x, u0.z, fmaf(s.y, u1.z, fmaf(s0t, v0.z, fmaf(s1t, v1.z, cb.z))));
  o.w = fmaf(s.x, u0.w, fmaf(s.y, u1.w, fmaf(s0t, v0.w, fmaf(s1t, v1.w, cb.w))));
  *(float4*)(out + n * 128 + kq) = o;
}

extern "C" void kernel_launch(void* const* d_in, const int* in_sizes, int n_in,
                              void* d_out, int out_size, void* d_ws, size_t ws_size,
                              hipStream_t stream) {
  const float* x        = (const float*)d_in[0];
  const int*   ei       = (const int*)d_in[1];
  const float* ea       = (const float*)d_in[2];
  const int*   tgt      = (const int*)d_in[3];
  const float* W_l      = (const float*)d_in[4];
  const float* b_l      = (const float*)d_in[5];
  const float* W_r      = (const float*)d_in[6];
  const float* b_r      = (const float*)d_in[7];
  const float* W_e      = (const float*)d_in[8];
  const float* att      = (const float*)d_in[9];
  const float* bias_out = (const float*)d_in[10];
  const float* W_fc     = (const float*)d_in[11];
  const float* b_fc     = (const float*)d_in[12];

  const int N = in_sizes[0];
  const int E = in_sizes[2];
  const int NB = (N + NPB - 1) / NPB;          // 782 buckets
  const int S_BLOCKS = (E + EPB - 1) / EPB;    // 1563 bin blocks

  const size_t sz_rec   = (size_t)S_BLOCKS * EPB * 16;
  const size_t sz_offs  = (size_t)S_BLOCKS * (NB + 1) * 4;  // row-major
  const size_t sz_offsT = (size_t)(NB + 1) * S_BLOCKS * 4;  // transposed
  const size_t sz_S     = (size_t)2 * N * 4;
  const size_t sz_C     = 4608;
  // largest P in {8,4,2} whose partial slab fits; SPP must stay <= 2*TB (=512)
  int P = 8;
  while (P > 2 &&
         sz_rec + sz_offs + sz_offsT + sz_S + sz_C +
             (size_t)NB * P * NPB * 6 * 4 > ws_size)
    P >>= 1;
  const int SPP = (S_BLOCKS + P - 1) / P;      // 196 @ P=8, 391 @ P=4

  char* p = (char*)d_ws;
  int4*  rec   = (int4*)p;                      p += sz_rec;
  int*   offs  = (int*)p;                       p += sz_offs;
  int*   offsT = (int*)p;                       p += sz_offsT;
  float* S     = (float*)p;                     p += sz_S;
  float* C     = (float*)p;                     p += sz_C;
  float* Spart = (float*)p;

  k_prep<<<1, 128, 0, stream>>>((const unsigned int*)ei, att, W_l, b_l, b_r,
                                bias_out, W_fc, b_fc, C);
  k_bin<<<S_BLOCKS, TB, 0, stream>>>(x, ei, ea, W_l, W_r, W_e, C,
                                     rec, offs, NB, S_BLOCKS, E);
  k_xpose<<<dim3((NB + 1 + TSZ - 1) / TSZ, (S_BLOCKS + TSZ - 1) / TSZ),
            256, 0, stream>>>(offs, offsT, NB + 1, S_BLOCKS);
  k_reduce<<<dim3(NB, P), TB, 0, stream>>>(rec, offsT, Spart, S_BLOCKS, SPP);
  k_fin<<<(N + 255) / 256, 256, 0, stream>>>(x, W_l, W_r, W_e, C, Spart, S, N, P);
  k_out<<<(N * 32 + 255) / 256, 256, 0, stream>>>(S, C, tgt, (float*)d_out, N);
}

// Round 9
// 201.337 us; speedup vs baseline: 2.6566x; 1.0360x over previous
//
#include <hip/hip_runtime.h>
#include <math.h>

// GATv2 (in_ch=1, edge_dim=1, H=2, C=64) + fc, collapsed to rank-1/rank-2 algebra.
//
// Round 14: algebraic strength reduction in k_bin/k_fin.
//   logit = sum_j a_j*lrelu(v_j) = 0.6*sum_j a_j v_j + 0.4*sum_j a_j |v_j|.
//   The linear term is precomputed per head as 4 scalars (LIN = [La,Lb,Lc,Ld],
//   dot with (xs,xt,ae,1)) via wave-shfl reduce in k_prep. Channel loop drops
//   5 FMA -> 4 FMA (abs is a free VOP3 modifier) and the A1 constant stream
//   disappears (6 -> 5 s_load streams). k_bin skeleton otherwise = proven R13
//   body (44.0us). Harness fillBuffer (~45us x2, 74% HBM) is a fixed floor.
//
// ws: rec[S_BLOCKS*1024] int4 | offs[S_BLOCKS*(NB+1)] int |
//     offsT[(NB+1)*S_BLOCKS] int | S[2N] f32 | C[1152] f32 |
//     Spart[NB*P*128*6] f32
// C layout: [0:128) A1 (legacy) | [128:256) A2 | [256:384) BASE | [384:896)
//     U0,U1,V0,V1 | [896:1024) CB | int[1024] w64 flag | [1028:1036) LIN h0,h1

#define LRELU_A1 0.6f   // leakyrelu(v) = 0.6 v + 0.4 |v|  (slope 0.2)
#define LRELU_A2 0.4f
#define TB       256
#define EPB      1024   // edges per bin block
#define NE       (EPB / TB)  // 4 edges per thread
#define NPB      128    // nodes per bucket (dst>>7)
#define NB_MAX   1024
#define SW       512    // sort window (records)
#define TSZ      32     // transpose tile

__global__ void k_prep(const unsigned int* __restrict__ ei,
                       const float* __restrict__ att,
                       const float* __restrict__ W_l,
                       const float* __restrict__ b_l, const float* __restrict__ b_r,
                       const float* __restrict__ W_r, const float* __restrict__ W_e,
                       const float* __restrict__ bias_out,
                       const float* __restrict__ W_fc, const float* __restrict__ b_fc,
                       float* __restrict__ C) {
  int j = threadIdx.x;
  unsigned long long nz = __ballot(j < 32 && ei[2 * j + 1] != 0u);
  if (j == 0) ((int*)C)[1024] = (nz == 0ull) ? 1 : 0;   // 1 => int64 indices
  if (j >= 128) return;
  float a = att[j];
  float t1 = LRELU_A1 * a;
  float bbj = b_l[j] + b_r[j];
  C[j] = t1;                    // A1 (legacy, unused by hot loops now)
  C[128 + j] = LRELU_A2 * a;    // A2
  C[256 + j] = bbj;             // BASE
  // per-head linear fold: LIN[h] = (0.6 sum a.wl, 0.6 sum a.wr, 0.6 sum a.we,
  //                                 0.6 sum a.(bl+br)) over the head's 64 ch
  {
    float sa = t1 * W_l[j], sb = t1 * W_r[j], sc = t1 * W_e[j], sd = t1 * bbj;
#pragma unroll
    for (int d = 32; d >= 1; d >>= 1) {
      sa += __shfl_down(sa, d);
      sb += __shfl_down(sb, d);
      sc += __shfl_down(sc, d);
      sd += __shfl_down(sd, d);
    }
    if ((j & 63) == 0) {
      int h = j >> 6;
      C[1028 + 4 * h + 0] = sa;
      C[1028 + 4 * h + 1] = sb;
      C[1028 + 4 * h + 2] = sc;
      C[1028 + 4 * h + 3] = sd;
    }
  }
  const float* wrow = W_fc + j * 256;
  float u0 = 0.f, u1 = 0.f, v0 = 0.f, v1 = 0.f, cb = b_fc[j];
  for (int c = 0; c < 64; c++) {
    u0 = fmaf(W_l[c],      wrow[c],       u0);
    u1 = fmaf(W_l[64 + c], wrow[64 + c],  u1);
    v0 = fmaf(W_l[c],      wrow[128 + c], v0);
    v1 = fmaf(W_l[64 + c], wrow[192 + c], v1);
  }
  for (int t = 0; t < 128; t++) {
    float gb = b_l[t] + bias_out[t];
    cb = fmaf(gb, wrow[t] + wrow[128 + t], cb);
  }
  C[384 + j] = u0;  // U0
  C[512 + j] = u1;  // U1
  C[640 + j] = v0;  // V0
  C[768 + j] = v1;  // V1
  C[896 + j] = cb;  // CB
}

#define CH_STEP(comp, ACC, i)                                                      \
  do {                                                                             \
    float v_ = fmaf(xs8[i], wl.comp, fmaf(xt8[i], wr.comp, fmaf(ae8[i], we.comp, bb.comp))); \
    ACC[i] = fmaf(a2.comp, fabsf(v_), ACC[i]);                                     \
  } while (0)

__global__ __launch_bounds__(TB, 4) void k_bin(
    const float* __restrict__ x, const int* __restrict__ ei,
    const float* __restrict__ ea,
    const float* __restrict__ WL, const float* __restrict__ WR,
    const float* __restrict__ WE, const float* __restrict__ C,
    int4* __restrict__ rec, int* __restrict__ offs,
    int NB, int S_BLOCKS, int E) {
  __shared__ int cnt[NB_MAX];
  __shared__ int pfx[NB_MAX + 1];
  __shared__ int wsum[4];
  const int tid = threadIdx.x;
  for (int i = tid; i < NB_MAX; i += TB) cnt[i] = 0;
  __syncthreads();

  const int e0 = blockIdx.x * EPB;
  const bool w64 = ((const int*)C)[1024] != 0;
  const float* A2 = C + 128;
  const float* BASE = C + 256;

  int de8[NE];
  float ae8[NE], xs8[NE], xt8[NE];
  bool ok[NE];
#pragma unroll
  for (int i = 0; i < NE; i++) {
    int e = e0 + i * TB + tid;   // coalesced per round
    ok[i] = (e < E);
    int ee = ok[i] ? e : 0;
    int s_ = w64 ? ei[2 * ee] : ei[ee];
    int d_ = w64 ? ei[2 * (E + ee)] : ei[E + ee];
    de8[i] = d_;
    ae8[i] = ea[ee];
    xs8[i] = x[s_];
    xt8[i] = x[d_];
  }
  float acc0[NE], acc1[NE];
#pragma unroll
  for (int i = 0; i < NE; i++) { acc0[i] = 0.f; acc1[i] = 0.f; }
#pragma unroll 2
  for (int jb = 0; jb < 64; jb += 4) {
    float4 wl = *(const float4*)(WL + jb);
    float4 wr = *(const float4*)(WR + jb);
    float4 we = *(const float4*)(WE + jb);
    float4 bb = *(const float4*)(BASE + jb);
    float4 a2 = *(const float4*)(A2 + jb);
#pragma unroll
    for (int i = 0; i < NE; i++) {
      CH_STEP(x, acc0, i); CH_STEP(y, acc0, i); CH_STEP(z, acc0, i); CH_STEP(w, acc0, i);
    }
  }
#pragma unroll 2
  for (int jb = 64; jb < 128; jb += 4) {
    float4 wl = *(const float4*)(WL + jb);
    float4 wr = *(const float4*)(WR + jb);
    float4 we = *(const float4*)(WE + jb);
    float4 bb = *(const float4*)(BASE + jb);
    float4 a2 = *(const float4*)(A2 + jb);
#pragma unroll
    for (int i = 0; i < NE; i++) {
      CH_STEP(x, acc1, i); CH_STEP(y, acc1, i); CH_STEP(z, acc1, i); CH_STEP(w, acc1, i);
    }
  }
  // payload -> registers; claim slots in LDS
  const float4 L0 = *(const float4*)(C + 1028);
  const float4 L1 = *(const float4*)(C + 1032);
  int b8[NE], slot8[NE], p0[NE], p1[NE], p2[NE], p3[NE];
#pragma unroll
  for (int i = 0; i < NE; i++) {
    int d_ = de8[i];
    b8[i] = d_ >> 7;
    float lin0 = fmaf(xs8[i], L0.x, fmaf(xt8[i], L0.y, fmaf(ae8[i], L0.z, L0.w)));
    float lin1 = fmaf(xs8[i], L1.x, fmaf(xt8[i], L1.y, fmaf(ae8[i], L1.z, L1.w)));
    p0[i] = __float_as_int(__expf(acc0[i] + lin0));
    p1[i] = __float_as_int(__expf(acc1[i] + lin1));
    p2[i] = __float_as_int(xs8[i]);
    p3[i] = (int)((__float_as_uint(ae8[i]) & ~127u) | (unsigned)(d_ & 127));
    slot8[i] = ok[i] ? atomicAdd(&cnt[b8[i]], 1) : 0;
  }
  __syncthreads();
  // exclusive scan of cnt[0..NB): per-thread 4 buckets, wave-shfl scan
  int l4[4], mysum = 0;
#pragma unroll
  for (int j = 0; j < 4; j++) {
    int idx = tid * 4 + j;
    l4[j] = (idx < NB) ? cnt[idx] : 0;
    mysum += l4[j];
  }
  const int lane = tid & 63, wv = tid >> 6;
  int inc = mysum;
#pragma unroll
  for (int d = 1; d < 64; d <<= 1) {
    int t = __shfl_up(inc, d);
    if (lane >= d) inc += t;
  }
  if (lane == 63) wsum[wv] = inc;
  __syncthreads();
  int wbase = 0;
#pragma unroll
  for (int w = 0; w < 4; w++) if (w < wv) wbase += wsum[w];
  int run = wbase + inc - mysum;
#pragma unroll
  for (int j = 0; j < 4; j++) {
    int idx = tid * 4 + j;
    if (idx < NB) { pfx[idx] = run; run += l4[j]; }
  }
  if (tid == 0) pfx[NB] = wsum[0] + wsum[1] + wsum[2] + wsum[3];
  __syncthreads();
  // coalesced offs[s][b] write (783 contiguous ints per block)
  int* myoffs = offs + (size_t)blockIdx.x * (NB + 1);
  for (int b = tid; b <= NB; b += TB) myoffs[b] = pfx[b];
  // direct-indexed drain from registers (random within 16KB block region; L2-local)
  int4* myrec = rec + (size_t)blockIdx.x * EPB;
#pragma unroll
  for (int i = 0; i < NE; i++) {
    if (ok[i]) myrec[pfx[b8[i]] + slot8[i]] = make_int4(p0[i], p1[i], p2[i], p3[i]);
  }
}

// Tiled transpose: offs[s][b] (s<S_BLOCKS rows, R=NB+1 cols) -> offsT[b][s].
// Both sides coalesced; kills the 4B-every-6.2KB line-RMW scatter k_bin had.
__global__ __launch_bounds__(256) void k_xpose(const int* __restrict__ offs,
                                               int* __restrict__ offsT,
                                               int R, int SB) {
  __shared__ int tile[TSZ][TSZ + 1];
  const int b0 = blockIdx.x * TSZ;   // col tile in offs (b axis)
  const int s0 = blockIdx.y * TSZ;   // row tile in offs (s axis)
  const int tx = threadIdx.x & 31, ty = threadIdx.x >> 5;  // 32x8
  for (int i = ty; i < TSZ; i += 8) {
    int s = s0 + i, b = b0 + tx;
    tile[i][tx] = (s < SB && b < R) ? offs[(size_t)s * R + b] : 0;
  }
  __syncthreads();
  for (int i = ty; i < TSZ; i += 8) {
    int b = b0 + i, s = s0 + tx;
    if (b < R && s < SB) offsT[(size_t)b * SB + s] = tile[tx][i];
  }
}

// One block per (bucket, part). part covers segments s in
// [part*SPP, min((part+1)*SPP, S_BLOCKS)), SPP <= 2*TB (host invariant).
// Thread tid owns segment tid (A) and tid+TB (B) as named scalars (no spill).
// Windowed counting sort by 7-bit node key, then per-node register reduction.
__global__ __launch_bounds__(TB, 4) void k_reduce(
    const int4* __restrict__ rec, const int* __restrict__ offsT,
    float* __restrict__ Spart, int S_BLOCKS, int SPP) {
  __shared__ int4 sorted[SW];          // 8 KB
  __shared__ int lut[SW];              // 2 KB
  __shared__ int cnt[NPB];             // histogram
  __shared__ int pos0[NPB];            // exclusive scan of cnt
  __shared__ int claim[NPB];           // scatter cursor
  __shared__ int wsum[4];
  const int tid = threadIdx.x;
  const int b = blockIdx.x;            // bucket
  const int part = blockIdx.y;

  // segment A = part*SPP + tid, segment B = part*SPP + tid + TB
  const int sA = part * SPP + tid;
  const int sB = sA + TB;
  int stA = 0, lenA = 0, stB = 0, lenB = 0;
  if (tid < SPP && sA < S_BLOCKS) {
    stA  = offsT[(size_t)b * S_BLOCKS + sA];
    lenA = offsT[(size_t)(b + 1) * S_BLOCKS + sA] - stA;
  }
  if (TB + tid < SPP && sB < S_BLOCKS) {
    stB  = offsT[(size_t)b * S_BLOCKS + sB];
    lenB = offsT[(size_t)(b + 1) * S_BLOCKS + sB] - stB;
  }
  const int rbA = sA * EPB + stA;      // global rec index of segment A start
  const int rbB = sB * EPB + stB;
  const int mysum = lenA + lenB;
  if (tid < NPB) cnt[tid] = 0;
  // wave-shfl exclusive scan of per-thread record counts
  const int lane = tid & 63, wv = tid >> 6;
  int inc = mysum;
#pragma unroll
  for (int d = 1; d < 64; d <<= 1) {
    int t = __shfl_up(inc, d);
    if (lane >= d) inc += t;
  }
  if (lane == 63) wsum[wv] = inc;
  __syncthreads();
  int wbase = 0;
#pragma unroll
  for (int w = 0; w < 4; w++) if (w < wv) wbase += wsum[w];
  const int T = wsum[0] + wsum[1] + wsum[2] + wsum[3];
  const int bsA = wbase + inc - mysum; // this thread's strip: [bsA, bsA+lenA+lenB)
  const int bsB = bsA + lenA;

  // per-node register accumulators (threads < NPB)
  float r0 = 0.f, r1 = 0.f, r2 = 0.f, r3 = 0.f, r4 = 0.f;
  int rc = 0;

  for (int w0 = 0; w0 < T; w0 += SW) {
    const int w1 = min(w0 + SW, T);
    // fill lut[w0..w1): each segment-owner scatters its records' rec indices
    {
      int lo = max(bsA, w0), hi = min(bsA + lenA, w1);
      for (int k = lo; k < hi; k++) lut[k - w0] = rbA + (k - bsA);
      lo = max(bsB, w0); hi = min(bsB + lenB, w1);
      for (int k = lo; k < hi; k++) lut[k - w0] = rbB + (k - bsB);
    }
    __syncthreads();
    // pass A: histogram node keys (no-return u32 atomic)
    for (int i = w0 + tid; i < w1; i += TB) {
      int4 r = rec[(size_t)(unsigned)lut[i - w0]];
      atomicAdd(&cnt[(int)((unsigned)r.w & 127u)], 1);
    }
    __syncthreads();
    // wave 0: exclusive scan of cnt[0..128) via shfl, init claim cursors
    if (tid < 64) {
      int c0 = cnt[2 * tid], c1 = cnt[2 * tid + 1];
      int s = c0 + c1;
      for (int d = 1; d < 64; d <<= 1) {
        int t = __shfl_up(s, d);
        if (tid >= d) s += t;
      }
      int excl = s - (c0 + c1);
      pos0[2 * tid] = excl;
      pos0[2 * tid + 1] = excl + c0;
      claim[2 * tid] = excl;
      claim[2 * tid + 1] = excl + c0;
    }
    __syncthreads();
    // pass B: re-read (cache-hot), claim sorted slot, scatter into LDS
    for (int i = w0 + tid; i < w1; i += TB) {
      int4 r = rec[(size_t)(unsigned)lut[i - w0]];
      int node = (int)((unsigned)r.w & 127u);
      int slot = atomicAdd(&claim[node], 1);
      sorted[slot] = r;
    }
    __syncthreads();
    // pass C: thread n walks node n's contiguous run, accumulates in regs
    if (tid < NPB) {
      int p = pos0[tid], c = cnt[tid];
      for (int k = 0; k < c; k++) {
        int4 r = sorted[p + k];
        float e0v = __int_as_float(r.x);
        float e1v = __int_as_float(r.y);
        float xsv = __int_as_float(r.z);
        float aev = __uint_as_float((unsigned)r.w & ~127u);
        r0 += e0v;
        r1 += e0v * xsv;
        r2 += e1v;
        r3 += e1v * xsv;
        r4 += aev;
      }
      rc += c;
      cnt[tid] = 0;   // reset for next window (after use)
    }
    __syncthreads();
  }
  // drain: 6 floats per node, contiguous 24 B per thread
  if (tid < NPB) {
    float* out = Spart + ((size_t)b * gridDim.y + part) * (NPB * 6) + tid * 6;
    out[0] = r0; out[1] = r1; out[2] = r2;
    out[3] = r3; out[4] = r4; out[5] = (float)rc;
  }
}

// Sum the P partials per node, then fused self-loop + S finalize.
__global__ __launch_bounds__(256) void k_fin(
    const float* __restrict__ x,
    const float* __restrict__ WL, const float* __restrict__ WR,
    const float* __restrict__ WE, const float* __restrict__ C,
    const float* __restrict__ Spart, float* __restrict__ S,
    int N, int P) {
  int n = blockIdx.x * blockDim.x + threadIdx.x;
  if (n >= N) return;
  int b = n >> 7, t = n & 127;
  const float* q0 = Spart + ((size_t)b * P) * (NPB * 6) + t * 6;
  float den0 = 0.f, num0 = 0.f, den1 = 0.f, num1 = 0.f, asum = 0.f, cntv = 0.f;
  for (int p = 0; p < P; p++) {
    const float* q = q0 + (size_t)p * (NPB * 6);
    float2 v0 = *(const float2*)(q);
    float2 v1 = *(const float2*)(q + 2);
    float2 v2 = *(const float2*)(q + 4);
    den0 += v0.x; num0 += v0.y;
    den1 += v1.x; num1 += v1.y;
    asum += v2.x; cntv += v2.y;
  }
  const float* A2 = C + 128;
  const float* BASE = C + 256;
  float xn = x[n];
  float am = asum / fmaxf(cntv, 1.0f);
  float acc0 = 0.f, acc1 = 0.f;
#pragma unroll 4
  for (int jb = 0; jb < 64; jb += 4) {
    float4 wl = *(const float4*)(WL + jb);
    float4 wr = *(const float4*)(WR + jb);
    float4 we = *(const float4*)(WE + jb);
    float4 bb = *(const float4*)(BASE + jb);
    float4 a2 = *(const float4*)(A2 + jb);
    float v;
    v = fmaf(xn, wl.x + wr.x, fmaf(am, we.x, bb.x)); acc0 = fmaf(a2.x, fabsf(v), acc0);
    v = fmaf(xn, wl.y + wr.y, fmaf(am, we.y, bb.y)); acc0 = fmaf(a2.y, fabsf(v), acc0);
    v = fmaf(xn, wl.z + wr.z, fmaf(am, we.z, bb.z)); acc0 = fmaf(a2.z, fabsf(v), acc0);
    v = fmaf(xn, wl.w + wr.w, fmaf(am, we.w, bb.w)); acc0 = fmaf(a2.w, fabsf(v), acc0);
  }
#pragma unroll 4
  for (int jb = 64; jb < 128; jb += 4) {
    float4 wl = *(const float4*)(WL + jb);
    float4 wr = *(const float4*)(WR + jb);
    float4 we = *(const float4*)(WE + jb);
    float4 bb = *(const float4*)(BASE + jb);
    float4 a2 = *(const float4*)(A2 + jb);
    float v;
    v = fmaf(xn, wl.x + wr.x, fmaf(am, we.x, bb.x)); acc1 = fmaf(a2.x, fabsf(v), acc1);
    v = fmaf(xn, wl.y + wr.y, fmaf(am, we.y, bb.y)); acc1 = fmaf(a2.y, fabsf(v), acc1);
    v = fmaf(xn, wl.z + wr.z, fmaf(am, we.z, bb.z)); acc1 = fmaf(a2.z, fabsf(v), acc1);
    v = fmaf(xn, wl.w + wr.w, fmaf(am, we.w, bb.w)); acc1 = fmaf(a2.w, fabsf(v), acc1);
  }
  const float4 L0 = *(const float4*)(C + 1028);
  const float4 L1 = *(const float4*)(C + 1032);
  float lin0 = fmaf(xn, L0.x + L0.y, fmaf(am, L0.z, L0.w));
  float lin1 = fmaf(xn, L1.x + L1.y, fmaf(am, L1.z, L1.w));
  float s0 = __expf(acc0 + lin0), s1 = __expf(acc1 + lin1);
  float2 sv;
  sv.x = (num0 + s0 * xn) / (den0 + s0);
  sv.y = (num1 + s1 * xn) / (den1 + s1);
  *(float2*)(S + 2 * n) = sv;
}

__global__ __launch_bounds__(256) void k_out(
    const float* __restrict__ S, const float* __restrict__ C,
    const int* __restrict__ tgtp, float* __restrict__ out, int N) {
  int g = blockIdx.x * blockDim.x + threadIdx.x;
  if (g >= N * 32) return;
  int n = g >> 5;
  int kq = (g & 31) * 4;
  int T = tgtp[0];  // low word valid for int32 and little-endian int64
  float s0t = S[2 * T], s1t = S[2 * T + 1];
  float2 s = *(const float2*)(S + 2 * n);
  float4 u0 = *(const float4*)(C + 384 + kq);
  float4 u1 = *(const float4*)(C + 512 + kq);
  float4 v0 = *(const float4*)(C + 640 + kq);
  float4 v1 = *(const float4*)(C + 768 + kq);
  float4 cb = *(const float4*)(C + 896 + kq);
  float4 o;
  o.x = fmaf(s.x, u0.x, fmaf(s.y, u1.x, fmaf(s0t, v0.x, fmaf(s1t, v1.x, cb.x))));
  o.y = fmaf(s.x, u0.y, fmaf(s.y, u1.y, fmaf(s0t, v0.y, fmaf(s1t, v1.y, cb.y))));
  o.z = fmaf(s.x, u0.z, fmaf(s.y, u1.z, fmaf(s0t, v0.z, fmaf(s1t, v1.z, cb.z))));
  o.w = fmaf(s.x, u0.w, fmaf(s.y, u1.w, fmaf(s0t, v0.w, fmaf(s1t, v1.w, cb.w))));
  *(float4*)(out + n * 128 + kq) = o;
}

extern "C" void kernel_launch(void* const* d_in, const int* in_sizes, int n_in,
                              void* d_out, int out_size, void* d_ws, size_t ws_size,
                              hipStream_t stream) {
  const float* x        = (const float*)d_in[0];
  const int*   ei       = (const int*)d_in[1];
  const float* ea       = (const float*)d_in[2];
  const int*   tgt      = (const int*)d_in[3];
  const float* W_l      = (const float*)d_in[4];
  const float* b_l      = (const float*)d_in[5];
  const float* W_r      = (const float*)d_in[6];
  const float* b_r      = (const float*)d_in[7];
  const float* W_e      = (const float*)d_in[8];
  const float* att      = (const float*)d_in[9];
  const float* bias_out = (const float*)d_in[10];
  const float* W_fc     = (const float*)d_in[11];
  const float* b_fc     = (const float*)d_in[12];

  const int N = in_sizes[0];
  const int E = in_sizes[2];
  const int NB = (N + NPB - 1) / NPB;          // 782 buckets
  const int S_BLOCKS = (E + EPB - 1) / EPB;    // 1563 bin blocks

  const size_t sz_rec   = (size_t)S_BLOCKS * EPB * 16;
  const size_t sz_offs  = (size_t)S_BLOCKS * (NB + 1) * 4;  // row-major
  const size_t sz_offsT = (size_t)(NB + 1) * S_BLOCKS * 4;  // transposed
  const size_t sz_S     = (size_t)2 * N * 4;
  const size_t sz_C     = 4608;
  // largest P in {8,4,2} whose partial slab fits; SPP must stay <= 2*TB (=512)
  int P = 8;
  while (P > 2 &&
         sz_rec + sz_offs + sz_offsT + sz_S + sz_C +
             (size_t)NB * P * NPB * 6 * 4 > ws_size)
    P >>= 1;
  const int SPP = (S_BLOCKS + P - 1) / P;      // 196 @ P=8, 391 @ P=4

  char* p = (char*)d_ws;
  int4*  rec   = (int4*)p;                      p += sz_rec;
  int*   offs  = (int*)p;                       p += sz_offs;
  int*   offsT = (int*)p;                       p += sz_offsT;
  float* S     = (float*)p;                     p += sz_S;
  float* C     = (float*)p;                     p += sz_C;
  float* Spart = (float*)p;

  k_prep<<<1, 128, 0, stream>>>((const unsigned int*)ei, att, W_l, b_l, b_r,
                                W_r, W_e, bias_out, W_fc, b_fc, C);
  k_bin<<<S_BLOCKS, TB, 0, stream>>>(x, ei, ea, W_l, W_r, W_e, C,
                                     rec, offs, NB, S_BLOCKS, E);
  k_xpose<<<dim3((NB + 1 + TSZ - 1) / TSZ, (S_BLOCKS + TSZ - 1) / TSZ),
            256, 0, stream>>>(offs, offsT, NB + 1, S_BLOCKS);
  k_reduce<<<dim3(NB, P), TB, 0, stream>>>(rec, offsT, Spart, S_BLOCKS, SPP);
  k_fin<<<(N + 255) / 256, 256, 0, stream>>>(x, W_l, W_r, W_e, C, Spart, S, N, P);
  k_out<<<(N * 32 + 255) / 256, 256, 0, stream>>>(S, C, tgt, (float*)d_out, N);
}

// Round 10
// 201.019 us; speedup vs baseline: 2.6608x; 1.0016x over previous
//
#include <hip/hip_runtime.h>
#include <math.h>

// GATv2 (in_ch=1, edge_dim=1, H=2, C=64) + fc, collapsed to rank-1/rank-2 algebra.
//
// Round 15: merge k_fin + k_out into k_fo (one block per 128-node bucket):
//   phase A: threads 0..127 compute their node's S into LDS (same math as old
//   k_fin via node_S()); thread 128 computes the TARGET node's S with the
//   identical code path (no extra critical path - same 512-FMA loop as phase A
//   threads). barrier. phase B: 256 threads write the 128x128 output tile
//   coalesced, S read from LDS. Removes one launch gap + the S global
//   round-trip; S slab dropped from ws. All other kernels byte-identical to
//   R14 (201.3us; harness fillBuffer ~88us is a fixed floor).
//
// ws: rec[S_BLOCKS*1024] int4 | offs[S_BLOCKS*(NB+1)] int |
//     offsT[(NB+1)*S_BLOCKS] int | C[1152] f32 | Spart[NB*P*128*6] f32
// C layout: [0:128) A1 (legacy) | [128:256) A2 | [256:384) BASE | [384:896)
//     U0,U1,V0,V1 | [896:1024) CB | int[1024] w64 flag | [1028:1036) LIN h0,h1

#define LRELU_A1 0.6f   // leakyrelu(v) = 0.6 v + 0.4 |v|  (slope 0.2)
#define LRELU_A2 0.4f
#define TB       256
#define EPB      1024   // edges per bin block
#define NE       (EPB / TB)  // 4 edges per thread
#define NPB      128    // nodes per bucket (dst>>7)
#define NB_MAX   1024
#define SW       512    // sort window (records)
#define TSZ      32     // transpose tile

__global__ void k_prep(const unsigned int* __restrict__ ei,
                       const float* __restrict__ att,
                       const float* __restrict__ W_l,
                       const float* __restrict__ b_l, const float* __restrict__ b_r,
                       const float* __restrict__ W_r, const float* __restrict__ W_e,
                       const float* __restrict__ bias_out,
                       const float* __restrict__ W_fc, const float* __restrict__ b_fc,
                       float* __restrict__ C) {
  int j = threadIdx.x;
  unsigned long long nz = __ballot(j < 32 && ei[2 * j + 1] != 0u);
  if (j == 0) ((int*)C)[1024] = (nz == 0ull) ? 1 : 0;   // 1 => int64 indices
  if (j >= 128) return;
  float a = att[j];
  float t1 = LRELU_A1 * a;
  float bbj = b_l[j] + b_r[j];
  C[j] = t1;                    // A1 (legacy, unused by hot loops now)
  C[128 + j] = LRELU_A2 * a;    // A2
  C[256 + j] = bbj;             // BASE
  // per-head linear fold: LIN[h] = (0.6 sum a.wl, 0.6 sum a.wr, 0.6 sum a.we,
  //                                 0.6 sum a.(bl+br)) over the head's 64 ch
  {
    float sa = t1 * W_l[j], sb = t1 * W_r[j], sc = t1 * W_e[j], sd = t1 * bbj;
#pragma unroll
    for (int d = 32; d >= 1; d >>= 1) {
      sa += __shfl_down(sa, d);
      sb += __shfl_down(sb, d);
      sc += __shfl_down(sc, d);
      sd += __shfl_down(sd, d);
    }
    if ((j & 63) == 0) {
      int h = j >> 6;
      C[1028 + 4 * h + 0] = sa;
      C[1028 + 4 * h + 1] = sb;
      C[1028 + 4 * h + 2] = sc;
      C[1028 + 4 * h + 3] = sd;
    }
  }
  const float* wrow = W_fc + j * 256;
  float u0 = 0.f, u1 = 0.f, v0 = 0.f, v1 = 0.f, cb = b_fc[j];
  for (int c = 0; c < 64; c++) {
    u0 = fmaf(W_l[c],      wrow[c],       u0);
    u1 = fmaf(W_l[64 + c], wrow[64 + c],  u1);
    v0 = fmaf(W_l[c],      wrow[128 + c], v0);
    v1 = fmaf(W_l[64 + c], wrow[192 + c], v1);
  }
  for (int t = 0; t < 128; t++) {
    float gb = b_l[t] + bias_out[t];
    cb = fmaf(gb, wrow[t] + wrow[128 + t], cb);
  }
  C[384 + j] = u0;  // U0
  C[512 + j] = u1;  // U1
  C[640 + j] = v0;  // V0
  C[768 + j] = v1;  // V1
  C[896 + j] = cb;  // CB
}

#define CH_STEP(comp, ACC, i)                                                      \
  do {                                                                             \
    float v_ = fmaf(xs8[i], wl.comp, fmaf(xt8[i], wr.comp, fmaf(ae8[i], we.comp, bb.comp))); \
    ACC[i] = fmaf(a2.comp, fabsf(v_), ACC[i]);                                     \
  } while (0)

__global__ __launch_bounds__(TB, 4) void k_bin(
    const float* __restrict__ x, const int* __restrict__ ei,
    const float* __restrict__ ea,
    const float* __restrict__ WL, const float* __restrict__ WR,
    const float* __restrict__ WE, const float* __restrict__ C,
    int4* __restrict__ rec, int* __restrict__ offs,
    int NB, int S_BLOCKS, int E) {
  __shared__ int cnt[NB_MAX];
  __shared__ int pfx[NB_MAX + 1];
  __shared__ int wsum[4];
  const int tid = threadIdx.x;
  for (int i = tid; i < NB_MAX; i += TB) cnt[i] = 0;
  __syncthreads();

  const int e0 = blockIdx.x * EPB;
  const bool w64 = ((const int*)C)[1024] != 0;
  const float* A2 = C + 128;
  const float* BASE = C + 256;

  int de8[NE];
  float ae8[NE], xs8[NE], xt8[NE];
  bool ok[NE];
#pragma unroll
  for (int i = 0; i < NE; i++) {
    int e = e0 + i * TB + tid;   // coalesced per round
    ok[i] = (e < E);
    int ee = ok[i] ? e : 0;
    int s_ = w64 ? ei[2 * ee] : ei[ee];
    int d_ = w64 ? ei[2 * (E + ee)] : ei[E + ee];
    de8[i] = d_;
    ae8[i] = ea[ee];
    xs8[i] = x[s_];
    xt8[i] = x[d_];
  }
  float acc0[NE], acc1[NE];
#pragma unroll
  for (int i = 0; i < NE; i++) { acc0[i] = 0.f; acc1[i] = 0.f; }
#pragma unroll 2
  for (int jb = 0; jb < 64; jb += 4) {
    float4 wl = *(const float4*)(WL + jb);
    float4 wr = *(const float4*)(WR + jb);
    float4 we = *(const float4*)(WE + jb);
    float4 bb = *(const float4*)(BASE + jb);
    float4 a2 = *(const float4*)(A2 + jb);
#pragma unroll
    for (int i = 0; i < NE; i++) {
      CH_STEP(x, acc0, i); CH_STEP(y, acc0, i); CH_STEP(z, acc0, i); CH_STEP(w, acc0, i);
    }
  }
#pragma unroll 2
  for (int jb = 64; jb < 128; jb += 4) {
    float4 wl = *(const float4*)(WL + jb);
    float4 wr = *(const float4*)(WR + jb);
    float4 we = *(const float4*)(WE + jb);
    float4 bb = *(const float4*)(BASE + jb);
    float4 a2 = *(const float4*)(A2 + jb);
#pragma unroll
    for (int i = 0; i < NE; i++) {
      CH_STEP(x, acc1, i); CH_STEP(y, acc1, i); CH_STEP(z, acc1, i); CH_STEP(w, acc1, i);
    }
  }
  // payload -> registers; claim slots in LDS
  const float4 L0 = *(const float4*)(C + 1028);
  const float4 L1 = *(const float4*)(C + 1032);
  int b8[NE], slot8[NE], p0[NE], p1[NE], p2[NE], p3[NE];
#pragma unroll
  for (int i = 0; i < NE; i++) {
    int d_ = de8[i];
    b8[i] = d_ >> 7;
    float lin0 = fmaf(xs8[i], L0.x, fmaf(xt8[i], L0.y, fmaf(ae8[i], L0.z, L0.w)));
    float lin1 = fmaf(xs8[i], L1.x, fmaf(xt8[i], L1.y, fmaf(ae8[i], L1.z, L1.w)));
    p0[i] = __float_as_int(__expf(acc0[i] + lin0));
    p1[i] = __float_as_int(__expf(acc1[i] + lin1));
    p2[i] = __float_as_int(xs8[i]);
    p3[i] = (int)((__float_as_uint(ae8[i]) & ~127u) | (unsigned)(d_ & 127));
    slot8[i] = ok[i] ? atomicAdd(&cnt[b8[i]], 1) : 0;
  }
  __syncthreads();
  // exclusive scan of cnt[0..NB): per-thread 4 buckets, wave-shfl scan
  int l4[4], mysum = 0;
#pragma unroll
  for (int j = 0; j < 4; j++) {
    int idx = tid * 4 + j;
    l4[j] = (idx < NB) ? cnt[idx] : 0;
    mysum += l4[j];
  }
  const int lane = tid & 63, wv = tid >> 6;
  int inc = mysum;
#pragma unroll
  for (int d = 1; d < 64; d <<= 1) {
    int t = __shfl_up(inc, d);
    if (lane >= d) inc += t;
  }
  if (lane == 63) wsum[wv] = inc;
  __syncthreads();
  int wbase = 0;
#pragma unroll
  for (int w = 0; w < 4; w++) if (w < wv) wbase += wsum[w];
  int run = wbase + inc - mysum;
#pragma unroll
  for (int j = 0; j < 4; j++) {
    int idx = tid * 4 + j;
    if (idx < NB) { pfx[idx] = run; run += l4[j]; }
  }
  if (tid == 0) pfx[NB] = wsum[0] + wsum[1] + wsum[2] + wsum[3];
  __syncthreads();
  // coalesced offs[s][b] write (783 contiguous ints per block)
  int* myoffs = offs + (size_t)blockIdx.x * (NB + 1);
  for (int b = tid; b <= NB; b += TB) myoffs[b] = pfx[b];
  // direct-indexed drain from registers (random within 16KB block region; L2-local)
  int4* myrec = rec + (size_t)blockIdx.x * EPB;
#pragma unroll
  for (int i = 0; i < NE; i++) {
    if (ok[i]) myrec[pfx[b8[i]] + slot8[i]] = make_int4(p0[i], p1[i], p2[i], p3[i]);
  }
}

// Tiled transpose: offs[s][b] (s<S_BLOCKS rows, R=NB+1 cols) -> offsT[b][s].
// Both sides coalesced; kills the 4B-every-6.2KB line-RMW scatter k_bin had.
__global__ __launch_bounds__(256) void k_xpose(const int* __restrict__ offs,
                                               int* __restrict__ offsT,
                                               int R, int SB) {
  __shared__ int tile[TSZ][TSZ + 1];
  const int b0 = blockIdx.x * TSZ;   // col tile in offs (b axis)
  const int s0 = blockIdx.y * TSZ;   // row tile in offs (s axis)
  const int tx = threadIdx.x & 31, ty = threadIdx.x >> 5;  // 32x8
  for (int i = ty; i < TSZ; i += 8) {
    int s = s0 + i, b = b0 + tx;
    tile[i][tx] = (s < SB && b < R) ? offs[(size_t)s * R + b] : 0;
  }
  __syncthreads();
  for (int i = ty; i < TSZ; i += 8) {
    int b = b0 + i, s = s0 + tx;
    if (b < R && s < SB) offsT[(size_t)b * SB + s] = tile[tx][i];
  }
}

// One block per (bucket, part). part covers segments s in
// [part*SPP, min((part+1)*SPP, S_BLOCKS)), SPP <= 2*TB (host invariant).
// Thread tid owns segment tid (A) and tid+TB (B) as named scalars (no spill).
// Windowed counting sort by 7-bit node key, then per-node register reduction.
__global__ __launch_bounds__(TB, 4) void k_reduce(
    const int4* __restrict__ rec, const int* __restrict__ offsT,
    float* __restrict__ Spart, int S_BLOCKS, int SPP) {
  __shared__ int4 sorted[SW];          // 8 KB
  __shared__ int lut[SW];              // 2 KB
  __shared__ int cnt[NPB];             // histogram
  __shared__ int pos0[NPB];            // exclusive scan of cnt
  __shared__ int claim[NPB];           // scatter cursor
  __shared__ int wsum[4];
  const int tid = threadIdx.x;
  const int b = blockIdx.x;            // bucket
  const int part = blockIdx.y;

  // segment A = part*SPP + tid, segment B = part*SPP + tid + TB
  const int sA = part * SPP + tid;
  const int sB = sA + TB;
  int stA = 0, lenA = 0, stB = 0, lenB = 0;
  if (tid < SPP && sA < S_BLOCKS) {
    stA  = offsT[(size_t)b * S_BLOCKS + sA];
    lenA = offsT[(size_t)(b + 1) * S_BLOCKS + sA] - stA;
  }
  if (TB + tid < SPP && sB < S_BLOCKS) {
    stB  = offsT[(size_t)b * S_BLOCKS + sB];
    lenB = offsT[(size_t)(b + 1) * S_BLOCKS + sB] - stB;
  }
  const int rbA = sA * EPB + stA;      // global rec index of segment A start
  const int rbB = sB * EPB + stB;
  const int mysum = lenA + lenB;
  if (tid < NPB) cnt[tid] = 0;
  // wave-shfl exclusive scan of per-thread record counts
  const int lane = tid & 63, wv = tid >> 6;
  int inc = mysum;
#pragma unroll
  for (int d = 1; d < 64; d <<= 1) {
    int t = __shfl_up(inc, d);
    if (lane >= d) inc += t;
  }
  if (lane == 63) wsum[wv] = inc;
  __syncthreads();
  int wbase = 0;
#pragma unroll
  for (int w = 0; w < 4; w++) if (w < wv) wbase += wsum[w];
  const int T = wsum[0] + wsum[1] + wsum[2] + wsum[3];
  const int bsA = wbase + inc - mysum; // this thread's strip: [bsA, bsA+lenA+lenB)
  const int bsB = bsA + lenA;

  // per-node register accumulators (threads < NPB)
  float r0 = 0.f, r1 = 0.f, r2 = 0.f, r3 = 0.f, r4 = 0.f;
  int rc = 0;

  for (int w0 = 0; w0 < T; w0 += SW) {
    const int w1 = min(w0 + SW, T);
    // fill lut[w0..w1): each segment-owner scatters its records' rec indices
    {
      int lo = max(bsA, w0), hi = min(bsA + lenA, w1);
      for (int k = lo; k < hi; k++) lut[k - w0] = rbA + (k - bsA);
      lo = max(bsB, w0); hi = min(bsB + lenB, w1);
      for (int k = lo; k < hi; k++) lut[k - w0] = rbB + (k - bsB);
    }
    __syncthreads();
    // pass A: histogram node keys (no-return u32 atomic)
    for (int i = w0 + tid; i < w1; i += TB) {
      int4 r = rec[(size_t)(unsigned)lut[i - w0]];
      atomicAdd(&cnt[(int)((unsigned)r.w & 127u)], 1);
    }
    __syncthreads();
    // wave 0: exclusive scan of cnt[0..128) via shfl, init claim cursors
    if (tid < 64) {
      int c0 = cnt[2 * tid], c1 = cnt[2 * tid + 1];
      int s = c0 + c1;
      for (int d = 1; d < 64; d <<= 1) {
        int t = __shfl_up(s, d);
        if (tid >= d) s += t;
      }
      int excl = s - (c0 + c1);
      pos0[2 * tid] = excl;
      pos0[2 * tid + 1] = excl + c0;
      claim[2 * tid] = excl;
      claim[2 * tid + 1] = excl + c0;
    }
    __syncthreads();
    // pass B: re-read (cache-hot), claim sorted slot, scatter into LDS
    for (int i = w0 + tid; i < w1; i += TB) {
      int4 r = rec[(size_t)(unsigned)lut[i - w0]];
      int node = (int)((unsigned)r.w & 127u);
      int slot = atomicAdd(&claim[node], 1);
      sorted[slot] = r;
    }
    __syncthreads();
    // pass C: thread n walks node n's contiguous run, accumulates in regs
    if (tid < NPB) {
      int p = pos0[tid], c = cnt[tid];
      for (int k = 0; k < c; k++) {
        int4 r = sorted[p + k];
        float e0v = __int_as_float(r.x);
        float e1v = __int_as_float(r.y);
        float xsv = __int_as_float(r.z);
        float aev = __uint_as_float((unsigned)r.w & ~127u);
        r0 += e0v;
        r1 += e0v * xsv;
        r2 += e1v;
        r3 += e1v * xsv;
        r4 += aev;
      }
      rc += c;
      cnt[tid] = 0;   // reset for next window (after use)
    }
    __syncthreads();
  }
  // drain: 6 floats per node, contiguous 24 B per thread
  if (tid < NPB) {
    float* out = Spart + ((size_t)b * gridDim.y + part) * (NPB * 6) + tid * 6;
    out[0] = r0; out[1] = r1; out[2] = r2;
    out[3] = r3; out[4] = r4; out[5] = (float)rc;
  }
}

// Per-node S (old k_fin body): sum P partials, self-loop, softmax finalize.
__device__ __forceinline__ float2 node_S(
    int n, const float* __restrict__ x,
    const float* __restrict__ WL, const float* __restrict__ WR,
    const float* __restrict__ WE, const float* __restrict__ C,
    const float* __restrict__ Spart, int P) {
  int b = n >> 7, t = n & 127;
  const float* q0 = Spart + ((size_t)b * P) * (NPB * 6) + t * 6;
  float den0 = 0.f, num0 = 0.f, den1 = 0.f, num1 = 0.f, asum = 0.f, cntv = 0.f;
  for (int p = 0; p < P; p++) {
    const float* q = q0 + (size_t)p * (NPB * 6);
    float2 v0 = *(const float2*)(q);
    float2 v1 = *(const float2*)(q + 2);
    float2 v2 = *(const float2*)(q + 4);
    den0 += v0.x; num0 += v0.y;
    den1 += v1.x; num1 += v1.y;
    asum += v2.x; cntv += v2.y;
  }
  const float* A2 = C + 128;
  const float* BASE = C + 256;
  float xn = x[n];
  float am = asum / fmaxf(cntv, 1.0f);
  float acc0 = 0.f, acc1 = 0.f;
#pragma unroll 4
  for (int jb = 0; jb < 64; jb += 4) {
    float4 wl = *(const float4*)(WL + jb);
    float4 wr = *(const float4*)(WR + jb);
    float4 we = *(const float4*)(WE + jb);
    float4 bb = *(const float4*)(BASE + jb);
    float4 a2 = *(const float4*)(A2 + jb);
    float v;
    v = fmaf(xn, wl.x + wr.x, fmaf(am, we.x, bb.x)); acc0 = fmaf(a2.x, fabsf(v), acc0);
    v = fmaf(xn, wl.y + wr.y, fmaf(am, we.y, bb.y)); acc0 = fmaf(a2.y, fabsf(v), acc0);
    v = fmaf(xn, wl.z + wr.z, fmaf(am, we.z, bb.z)); acc0 = fmaf(a2.z, fabsf(v), acc0);
    v = fmaf(xn, wl.w + wr.w, fmaf(am, we.w, bb.w)); acc0 = fmaf(a2.w, fabsf(v), acc0);
  }
#pragma unroll 4
  for (int jb = 64; jb < 128; jb += 4) {
    float4 wl = *(const float4*)(WL + jb);
    float4 wr = *(const float4*)(WR + jb);
    float4 we = *(const float4*)(WE + jb);
    float4 bb = *(const float4*)(BASE + jb);
    float4 a2 = *(const float4*)(A2 + jb);
    float v;
    v = fmaf(xn, wl.x + wr.x, fmaf(am, we.x, bb.x)); acc1 = fmaf(a2.x, fabsf(v), acc1);
    v = fmaf(xn, wl.y + wr.y, fmaf(am, we.y, bb.y)); acc1 = fmaf(a2.y, fabsf(v), acc1);
    v = fmaf(xn, wl.z + wr.z, fmaf(am, we.z, bb.z)); acc1 = fmaf(a2.z, fabsf(v), acc1);
    v = fmaf(xn, wl.w + wr.w, fmaf(am, we.w, bb.w)); acc1 = fmaf(a2.w, fabsf(v), acc1);
  }
  const float4 L0 = *(const float4*)(C + 1028);
  const float4 L1 = *(const float4*)(C + 1032);
  float lin0 = fmaf(xn, L0.x + L0.y, fmaf(am, L0.z, L0.w));
  float lin1 = fmaf(xn, L1.x + L1.y, fmaf(am, L1.z, L1.w));
  float s0 = __expf(acc0 + lin0), s1 = __expf(acc1 + lin1);
  float2 sv;
  sv.x = (num0 + s0 * xn) / (den0 + s0);
  sv.y = (num1 + s1 * xn) / (den1 + s1);
  return sv;
}

// Fused finalize + output: one block per bucket. Phase A: threads 0..127
// compute their node's S into LDS; thread 128 computes the target node's S
// (identical code path, same per-thread cost as phase A). Phase B: 256
// threads write the 128x128 output tile coalesced.
__global__ __launch_bounds__(256) void k_fo(
    const float* __restrict__ x,
    const float* __restrict__ WL, const float* __restrict__ WR,
    const float* __restrict__ WE, const float* __restrict__ C,
    const float* __restrict__ Spart, const int* __restrict__ tgtp,
    float* __restrict__ out, int N, int P) {
  __shared__ float sS[2 * NPB + 2];
  const int tid = threadIdx.x;
  const int b = blockIdx.x;
  if (tid < NPB) {
    int n = b * NPB + tid;
    if (n < N) {
      float2 sv = node_S(n, x, WL, WR, WE, C, Spart, P);
      sS[2 * tid] = sv.x;
      sS[2 * tid + 1] = sv.y;
    }
  } else if (tid == NPB) {
    int T = tgtp[0];  // low word valid for int32 and little-endian int64
    float2 sv = node_S(T, x, WL, WR, WE, C, Spart, P);
    sS[2 * NPB] = sv.x;
    sS[2 * NPB + 1] = sv.y;
  }
  __syncthreads();
  const float s0t = sS[2 * NPB], s1t = sS[2 * NPB + 1];
#pragma unroll
  for (int it = 0; it < (NPB * 32) / 256; ++it) {   // 16 iterations
    int g = it * 256 + tid;
    int nl = g >> 5;            // local node 0..127
    int kq = (g & 31) * 4;      // output quad 0..124
    int n = b * NPB + nl;
    if (n < N) {
      float sx = sS[2 * nl], sy = sS[2 * nl + 1];
      float4 u0 = *(const float4*)(C + 384 + kq);
      float4 u1 = *(const float4*)(C + 512 + kq);
      float4 v0 = *(const float4*)(C + 640 + kq);
      float4 v1 = *(const float4*)(C + 768 + kq);
      float4 cb = *(const float4*)(C + 896 + kq);
      float4 o;
      o.x = fmaf(sx, u0.x, fmaf(sy, u1.x, fmaf(s0t, v0.x, fmaf(s1t, v1.x, cb.x))));
      o.y = fmaf(sx, u0.y, fmaf(sy, u1.y, fmaf(s0t, v0.y, fmaf(s1t, v1.y, cb.y))));
      o.z = fmaf(sx, u0.z, fmaf(sy, u1.z, fmaf(s0t, v0.z, fmaf(s1t, v1.z, cb.z))));
      o.w = fmaf(sx, u0.w, fmaf(sy, u1.w, fmaf(s0t, v0.w, fmaf(s1t, v1.w, cb.w))));
      *(float4*)(out + (size_t)n * 128 + kq) = o;
    }
  }
}

extern "C" void kernel_launch(void* const* d_in, const int* in_sizes, int n_in,
                              void* d_out, int out_size, void* d_ws, size_t ws_size,
                              hipStream_t stream) {
  const float* x        = (const float*)d_in[0];
  const int*   ei       = (const int*)d_in[1];
  const float* ea       = (const float*)d_in[2];
  const int*   tgt      = (const int*)d_in[3];
  const float* W_l      = (const float*)d_in[4];
  const float* b_l      = (const float*)d_in[5];
  const float* W_r      = (const float*)d_in[6];
  const float* b_r      = (const float*)d_in[7];
  const float* W_e      = (const float*)d_in[8];
  const float* att      = (const float*)d_in[9];
  const float* bias_out = (const float*)d_in[10];
  const float* W_fc     = (const float*)d_in[11];
  const float* b_fc     = (const float*)d_in[12];

  const int N = in_sizes[0];
  const int E = in_sizes[2];
  const int NB = (N + NPB - 1) / NPB;          // 782 buckets
  const int S_BLOCKS = (E + EPB - 1) / EPB;    // 1563 bin blocks

  const size_t sz_rec   = (size_t)S_BLOCKS * EPB * 16;
  const size_t sz_offs  = (size_t)S_BLOCKS * (NB + 1) * 4;  // row-major
  const size_t sz_offsT = (size_t)(NB + 1) * S_BLOCKS * 4;  // transposed
  const size_t sz_C     = 4608;
  // largest P in {8,4} whose partial slab fits; SPP must stay <= 2*TB (=512)
  int P = 8;
  while (P > 2 &&
         sz_rec + sz_offs + sz_offsT + sz_C +
             (size_t)NB * P * NPB * 6 * 4 > ws_size)
    P >>= 1;
  const int SPP = (S_BLOCKS + P - 1) / P;      // 196 @ P=8, 391 @ P=4

  char* p = (char*)d_ws;
  int4*  rec   = (int4*)p;                      p += sz_rec;
  int*   offs  = (int*)p;                       p += sz_offs;
  int*   offsT = (int*)p;                       p += sz_offsT;
  float* C     = (float*)p;                     p += sz_C;
  float* Spart = (float*)p;

  k_prep<<<1, 128, 0, stream>>>((const unsigned int*)ei, att, W_l, b_l, b_r,
                                W_r, W_e, bias_out, W_fc, b_fc, C);
  k_bin<<<S_BLOCKS, TB, 0, stream>>>(x, ei, ea, W_l, W_r, W_e, C,
                                     rec, offs, NB, S_BLOCKS, E);
  k_xpose<<<dim3((NB + 1 + TSZ - 1) / TSZ, (S_BLOCKS + TSZ - 1) / TSZ),
            256, 0, stream>>>(offs, offsT, NB + 1, S_BLOCKS);
  k_reduce<<<dim3(NB, P), TB, 0, stream>>>(rec, offsT, Spart, S_BLOCKS, SPP);
  k_fo<<<NB, 256, 0, stream>>>(x, W_l, W_r, W_e, C, Spart, tgt,
                               (float*)d_out, N, P);
}